// Round 22
// baseline (281.887 us; speedup 1.0000x reference)
//
#include <hip/hip_runtime.h>

#define D 64
#define CHUNK 32      // sorted entries per wave in the flat gather
#define NGROUP 8      // dst-range groups (one per XCD)
#define BIN_EPT 4     // edges per thread in the binning kernel
#define BIN_TILE 1024 // edges per tile (256 threads x BIN_EPT)
#define SENTINEL 0xFFFFFFFFu

// ---------------------------------------------------------------------------
// edge_index dtype detection (int32 vs int64), done per-block on device.
// ---------------------------------------------------------------------------
#define DETECT_IS64(ei)                                        \
  __shared__ int s_is64;                                       \
  if (threadIdx.x == 0) {                                      \
    const unsigned int* w_ = (const unsigned int*)(ei);        \
    int is64_ = 1;                                             \
    for (int i_ = 0; i_ < 64; ++i_) {                          \
      if (w_[2 * i_ + 1] != 0u) { is64_ = 0; break; }          \
    }                                                          \
    s_is64 = is64_;                                            \
  }                                                            \
  __syncthreads();

#define EDGE_GRID 4096
#define EDGE_BLOCK 256
#define SCAN_CHUNKS 8192

// bcnt layout: counter (g, s) at bcnt[(g*8+s)*16] — one 64B line each.
// Counter (g,s) is ONLY touched by blocks with blockIdx&7==s (XCD s):
// r21 lesson — a single shared bcnt[8] line serialized all 1563 blocks'
// value-returning reservations across 8 XCDs (~50ns/transfer = the whole
// 74us dispatch). XCD-local counters never migrate.
#define BCNT_IDX(g, s) (((g) * 8 + (s)) * 16)
#define BCNT_INTS (NGROUP * 8 * 16)

// ---------------------------------------------------------------------------
// Kernel 1: BIN + HIST fused, XCD-sharded reservations, line-aligned runs.
// Per 1024-edge tile: LDS-count per group -> reserve (rounded up to 16
// entries = 64B) from bcnt[g][blockIdx&7] (XCD-local line) -> write packed
// (dstLocal<<shift|src) entries + SENTINEL pads into subregion (g, s).
// Histogram atomicAdd(&C[dst],1) is non-returning -> ~305 G/s (r1).
// ---------------------------------------------------------------------------
__global__ __launch_bounds__(256) void gin_bin(
    const void* __restrict__ edge_index, int* __restrict__ C,
    int* __restrict__ bcnt, unsigned int* __restrict__ bucket,
    int n_edges, int n_nodes, int capSub, int shift_src) {
  DETECT_IS64(edge_index);
  const int* ei32 = (const int*)edge_index;
  const long long* ei64 = (const long long*)edge_index;
  __shared__ int lcnt[NGROUP];
  __shared__ int lbase[NGROUP];
  const int tid = (int)threadIdx.x;
  const int sub = (int)(blockIdx.x & 7);  // this block's XCD slot
  const int ntiles = (n_edges + BIN_TILE - 1) / BIN_TILE;

  for (int t = (int)blockIdx.x; t < ntiles; t += (int)gridDim.x) {
    if (tid < NGROUP) lcnt[tid] = 0;
    __syncthreads();

    int g[BIN_EPT], pos[BIN_EPT];
    unsigned int pk[BIN_EPT];
#pragma unroll
    for (int k = 0; k < BIN_EPT; ++k) {
      const int e = t * BIN_TILE + tid + k * 256;  // coalesced per k
      g[k] = -1;
      if (e < n_edges) {
        int src, dst;
        if (s_is64) {
          src = (int)ei64[e];
          dst = (int)ei64[n_edges + e];
        } else {
          src = ei32[e];
          dst = ei32[n_edges + e];
        }
        const int gg = (int)(((long long)dst * NGROUP) / n_nodes);
        const int nlo = (int)(((long long)n_nodes * gg) / NGROUP);
        g[k] = gg;
        pk[k] = ((unsigned int)(dst - nlo) << shift_src) | (unsigned int)src;
        atomicAdd(&C[dst], 1);                  // fused histogram
        pos[k] = atomicAdd(&lcnt[gg], 1);       // LDS cursor
      }
    }
    __syncthreads();
    if (tid < NGROUP) {
      const int padded = (lcnt[tid] + 15) & ~15;  // 64B-aligned reservation
      lbase[tid] = atomicAdd(&bcnt[BCNT_IDX(tid, sub)], padded);
    }
    __syncthreads();
#pragma unroll
    for (int k = 0; k < BIN_EPT; ++k) {
      if (g[k] >= 0) {
        bucket[(size_t)(g[k] * 8 + sub) * capSub + lbase[g[k]] + pos[k]] =
            pk[k];
      }
    }
    // sentinel-fill the pad slots (same block owns the whole run)
    for (int gg = 0; gg < NGROUP; ++gg) {
      const int c = lcnt[gg];
      const int padded = (c + 15) & ~15;
      for (int i = c + tid; i < padded; i += 256) {
        bucket[(size_t)(gg * 8 + sub) * capSub + lbase[gg] + i] = SENTINEL;
      }
    }
    __syncthreads();  // protect lcnt reset next iteration
  }
}

// ---------------------------------------------------------------------------
// Kernels 2a/2b/2c: in-place exclusive scan of C[total], SCAN_CHUNKS chunks.
// ---------------------------------------------------------------------------
__global__ __launch_bounds__(256) void gin_scan_a(
    const int* __restrict__ C, int* __restrict__ tsum, int total, int chunk) {
  const int t = (int)(blockIdx.x * blockDim.x + threadIdx.x);
  if (t >= SCAN_CHUNKS) return;
  const int beg = t * chunk;
  const int end = min(beg + chunk, total);
  int s = 0;
  for (int i = beg; i < end; ++i) s += C[i];
  tsum[t] = s;
}

__global__ __launch_bounds__(1024) void gin_scan_b(int* __restrict__ tsum) {
  __shared__ int ls[1024];
  const int t = threadIdx.x;
  int v[8];
  int s = 0;
#pragma unroll
  for (int i = 0; i < 8; ++i) {
    v[i] = tsum[t * 8 + i];
    s += v[i];
  }
  ls[t] = s;
  __syncthreads();
  for (int o = 1; o < 1024; o <<= 1) {
    const int a = (t >= o) ? ls[t - o] : 0;
    __syncthreads();
    ls[t] += a;
    __syncthreads();
  }
  int run = ls[t] - s;
#pragma unroll
  for (int i = 0; i < 8; ++i) {
    tsum[t * 8 + i] = run;
    run += v[i];
  }
}

__global__ __launch_bounds__(256) void gin_scan_c(
    int* __restrict__ C, const int* __restrict__ tsum, int total, int chunk) {
  const int t = (int)(blockIdx.x * blockDim.x + threadIdx.x);
  if (t >= SCAN_CHUNKS) return;
  const int beg = t * chunk;
  const int end = min(beg + chunk, total);
  int run = tsum[t];
  for (int i = beg; i < end; ++i) {
    const int c = C[i];
    C[i] = run;
    run += c;
  }
}

// ---------------------------------------------------------------------------
// Kernel 3: per-group placement from the 8 packed subregions of group g,
// skipping sentinels. Group g's blocks (b&7==g -> XCD g) read ONLY their
// ~1MB of bucket while writing their 800KB sorted region + cursors: fits
// the 4MB XCD L2. After this kernel, C[k] = prefix[k+1].
// ---------------------------------------------------------------------------
__global__ __launch_bounds__(256) void gin_place_bucket(
    const unsigned int* __restrict__ bucket, const int* __restrict__ bcnt,
    int* __restrict__ C, int* __restrict__ sorted_src,
    int n_nodes, int capSub, int shift_src) {
  const int g = (int)(blockIdx.x & (NGROUP - 1));
  const int nlo = (int)(((long long)n_nodes * g) / NGROUP);
  const unsigned int mask = (1u << shift_src) - 1u;
  const int i0 = (int)((blockIdx.x >> 3) * blockDim.x + threadIdx.x);
  const int stride = (int)((gridDim.x >> 3) * blockDim.x);
  for (int sub = 0; sub < 8; ++sub) {
    const int cnt = bcnt[BCNT_IDX(g, sub)];
    const unsigned int* bg = bucket + (size_t)(g * 8 + sub) * capSub;
    for (int i = i0; i < cnt; i += stride) {
      const unsigned int e = bg[i];
      if (e == SENTINEL) continue;  // pad slot
      const int src = (int)(e & mask);
      const int dst = nlo + (int)(e >> shift_src);
      const int pos = atomicAdd(&C[dst], 1);
      sorted_src[pos] = src;
    }
  }
}

// ---------------------------------------------------------------------------
// Kernel 3.5: per-chunk segment-start lookup. cs[w] = first k, C[k] > w*CHUNK.
// ---------------------------------------------------------------------------
__global__ __launch_bounds__(256) void gin_chunkstart(
    const int* __restrict__ C, int* __restrict__ cs, int n_nodes,
    int nchunks) {
  const int t = (int)(blockIdx.x * blockDim.x + threadIdx.x);
  if (t >= nchunks) return;
  const int start = t * CHUNK;
  int lo = 0, hi = n_nodes - 1;
  while (lo < hi) {
    const int mid = (lo + hi) >> 1;
    if (C[mid] > start) hi = mid; else lo = mid + 1;
  }
  cs[t] = lo;
}

// ---------------------------------------------------------------------------
// Kernel 4: FLAT segmented-sum gather, CHUNK=32, precomputed chunk starts.
// srcs staged into SGPRs (readfirstlane); 32 independent 256B row reads in
// flight. Interior segments plain-store; boundary segments atomicAdd (agg
// pre-zeroed; degree-0 nodes stay zero).
// ---------------------------------------------------------------------------
__global__ __launch_bounds__(256) void gin_gather_flat(
    const float* __restrict__ x, const int* __restrict__ C,
    const int* __restrict__ sorted_src, const int* __restrict__ cs,
    float* __restrict__ agg, int n_nodes, int n_edges) {
  const int lane = (int)(threadIdx.x & 63);
  const int wave = (int)((blockIdx.x * blockDim.x + threadIdx.x) >> 6);
  const int start = wave * CHUNK;
  if (start >= n_edges) return;
  const int cend = min(start + CHUNK, n_edges);

  int srcs[CHUNK];
#pragma unroll
  for (int i = 0; i < CHUNK; ++i) {
    srcs[i] = __builtin_amdgcn_readfirstlane(
        sorted_src[min(start + i, n_edges - 1)]);
  }
  float rows[CHUNK];
#pragma unroll
  for (int i = 0; i < CHUNK; ++i) {
    rows[i] = x[(size_t)srcs[i] * D + lane];
  }

  int k = cs[wave];
  int end = C[k];
  int segbeg = (k == 0) ? 0 : C[k - 1];

  float acc = 0.0f;
  int runstart = start;
#pragma unroll
  for (int i = 0; i < CHUNK; ++i) {
    const int pos = start + i;
    if (pos >= cend) break;  // tail chunk only
    acc += rows[i];
    if (pos + 1 == end) {
      const size_t off = (size_t)k * D + lane;
      if (segbeg >= start) {
        agg[off] = acc;               // interior: sole writer
      } else {
        atomicAdd(&agg[off], acc);    // crosses chunk start
      }
      acc = 0.0f;
      runstart = pos + 1;
      if (pos + 1 < cend) {
        segbeg = end;
        ++k;
        end = C[k];
        while (end == segbeg) { ++k; end = C[k]; }  // skip empty nodes
      }
    }
  }
  if (runstart < cend) {
    atomicAdd(&agg[(size_t)k * D + lane], acc);  // trailing open run
  }
}

// ---------------------------------------------------------------------------
// Mid-path fallback kernels (read edge_index directly; r16 behavior).
// ---------------------------------------------------------------------------
__global__ __launch_bounds__(256) void gin_hist_ranged(
    const void* __restrict__ edge_index, int* __restrict__ C,
    int n_edges, int n_nodes) {
  DETECT_IS64(edge_index);
  const int* ei32 = (const int*)edge_index;
  const long long* ei64 = (const long long*)edge_index;
  const int r = (int)(blockIdx.x & (NGROUP - 1));
  const int nlo = (int)(((long long)n_nodes * r) / NGROUP);
  const int nhi = (int)(((long long)n_nodes * (r + 1)) / NGROUP);
  const int i = (int)((blockIdx.x >> 3) * blockDim.x + threadIdx.x);
  const int stride = (int)((gridDim.x >> 3) * blockDim.x);
  for (int e = i; e < n_edges; e += stride) {
    const int dst = s_is64 ? (int)ei64[n_edges + e] : ei32[n_edges + e];
    if (dst >= nlo && dst < nhi) atomicAdd(&C[dst], 1);
  }
}

__global__ __launch_bounds__(256) void gin_place_ranged(
    const void* __restrict__ edge_index, int* __restrict__ C,
    int* __restrict__ sorted_src, int n_edges, int n_nodes) {
  DETECT_IS64(edge_index);
  const int* ei32 = (const int*)edge_index;
  const long long* ei64 = (const long long*)edge_index;
  const int r = (int)(blockIdx.x & (NGROUP - 1));
  const int nlo = (int)(((long long)n_nodes * r) / NGROUP);
  const int nhi = (int)(((long long)n_nodes * (r + 1)) / NGROUP);
  const int i = (int)((blockIdx.x >> 3) * blockDim.x + threadIdx.x);
  const int stride = (int)((gridDim.x >> 3) * blockDim.x);
  for (int e = i; e < n_edges; e += stride) {
    const int dst = s_is64 ? (int)ei64[n_edges + e] : ei32[n_edges + e];
    if (dst >= nlo && dst < nhi) {
      const int src = s_is64 ? (int)ei64[e] : ei32[e];
      const int pos = atomicAdd(&C[dst], 1);
      sorted_src[pos] = src;
    }
  }
}

// ---------------------------------------------------------------------------
// Last-resort fallback scatter: scalar float atomics, wave per edge.
// ---------------------------------------------------------------------------
__global__ __launch_bounds__(256) void gin_scatter_atomic(
    const float* __restrict__ x, const void* __restrict__ edge_index,
    float* __restrict__ agg, int n_edges) {
  DETECT_IS64(edge_index);
  const int* ei32 = (const int*)edge_index;
  const long long* ei64 = (const long long*)edge_index;
  const int lane = threadIdx.x & 63;
  int wave = (int)((blockIdx.x * blockDim.x + threadIdx.x) >> 6);
  const int nwaves = (int)((gridDim.x * blockDim.x) >> 6);
  for (int e = wave; e < n_edges; e += nwaves) {
    int src, dst;
    if (s_is64) {
      src = (int)ei64[e];
      dst = (int)ei64[n_edges + e];
    } else {
      src = ei32[e];
      dst = ei32[n_edges + e];
    }
    atomicAdd(&agg[(size_t)dst * D + lane], x[(size_t)src * D + lane]);
  }
}

// ---------------------------------------------------------------------------
// Kernel 5: block-tiled MLP (vector f32 GEMM). Unchanged from round 10/11.
// ---------------------------------------------------------------------------
__global__ __launch_bounds__(256) void gin_mlp_tiled(
    const float* __restrict__ x,
    const float* __restrict__ agg_in,
    const float* __restrict__ eps_p,
    const float* __restrict__ W1, const float* __restrict__ b1,
    const float* __restrict__ W2, const float* __restrict__ b2,
    float* __restrict__ out,
    int n_nodes) {
  __shared__ float zs[128 * 72];   // z tile; reused for h
  __shared__ float w1s[64 * 64];
  __shared__ float w2s[64 * 64];

  const int t = (int)threadIdx.x;
  const int base = (int)blockIdx.x * 128;
  const float scale = 1.0f + eps_p[0];

  {
    const float4* W1v = (const float4*)W1;
    const float4* W2v = (const float4*)W2;
#pragma unroll
    for (int i = 0; i < 4; ++i) {
      const int idx = t + 256 * i;
      const int j = idx >> 4;
      const int kq = idx & 15;
      const int slot = kq ^ ((j >> 2) & 7);
      *(float4*)&w1s[j * 64 + slot * 4] = W1v[idx];
      *(float4*)&w2s[j * 64 + slot * 4] = W2v[idx];
    }
  }

  {
#pragma unroll
    for (int i = 0; i < 8; ++i) {
      const int idx = t + 256 * i;
      const int row = idx >> 4;
      const int kq = idx & 15;
      const int g = base + row;
      float4 zv;
      zv.x = 0.0f; zv.y = 0.0f; zv.z = 0.0f; zv.w = 0.0f;
      if (g < n_nodes) {
        const float4 xv = *(const float4*)(x + (size_t)g * D + kq * 4);
        const float4 av = *(const float4*)(agg_in + (size_t)g * D + kq * 4);
        zv.x = scale * xv.x + av.x;
        zv.y = scale * xv.y + av.y;
        zv.z = scale * xv.z + av.z;
        zv.w = scale * xv.w + av.w;
      }
      *(float4*)&zs[row * 72 + kq * 4] = zv;
    }
  }
  __syncthreads();

  const int jg = t & 15;
  const int mg = t >> 4;
  const float4 b1q = ((const float4*)b1)[jg];
  const float4 b2q = ((const float4*)b2)[jg];
  const int wswz = (jg & 7);

  float acc[8][4];
#pragma unroll
  for (int r = 0; r < 8; ++r) {
    acc[r][0] = b1q.x; acc[r][1] = b1q.y;
    acc[r][2] = b1q.z; acc[r][3] = b1q.w;
  }

#pragma unroll 4
  for (int kq = 0; kq < 16; ++kq) {
    float4 wq[4];
#pragma unroll
    for (int c = 0; c < 4; ++c) {
      wq[c] = *(const float4*)&w1s[(4 * jg + c) * 64 + ((kq ^ wswz) * 4)];
    }
#pragma unroll
    for (int r = 0; r < 8; ++r) {
      const float4 zq = *(const float4*)&zs[(r * 16 + mg) * 72 + kq * 4];
#pragma unroll
      for (int c = 0; c < 4; ++c) {
        acc[r][c] += zq.x * wq[c].x + zq.y * wq[c].y +
                     zq.z * wq[c].z + zq.w * wq[c].w;
      }
    }
  }

  __syncthreads();
#pragma unroll
  for (int r = 0; r < 8; ++r) {
    float4 hv;
    hv.x = fmaxf(acc[r][0], 0.0f);
    hv.y = fmaxf(acc[r][1], 0.0f);
    hv.z = fmaxf(acc[r][2], 0.0f);
    hv.w = fmaxf(acc[r][3], 0.0f);
    *(float4*)&zs[(r * 16 + mg) * 72 + jg * 4] = hv;
  }
  __syncthreads();

#pragma unroll
  for (int r = 0; r < 8; ++r) {
    acc[r][0] = b2q.x; acc[r][1] = b2q.y;
    acc[r][2] = b2q.z; acc[r][3] = b2q.w;
  }
#pragma unroll 4
  for (int kq = 0; kq < 16; ++kq) {
    float4 wq[4];
#pragma unroll
    for (int c = 0; c < 4; ++c) {
      wq[c] = *(const float4*)&w2s[(4 * jg + c) * 64 + ((kq ^ wswz) * 4)];
    }
#pragma unroll
    for (int r = 0; r < 8; ++r) {
      const float4 zq = *(const float4*)&zs[(r * 16 + mg) * 72 + kq * 4];
#pragma unroll
      for (int c = 0; c < 4; ++c) {
        acc[r][c] += zq.x * wq[c].x + zq.y * wq[c].y +
                     zq.z * wq[c].z + zq.w * wq[c].w;
      }
    }
  }

#pragma unroll
  for (int r = 0; r < 8; ++r) {
    const int g = base + r * 16 + mg;
    if (g < n_nodes) {
      float4 ov;
      ov.x = acc[r][0]; ov.y = acc[r][1];
      ov.z = acc[r][2]; ov.w = acc[r][3];
      *(float4*)(out + (size_t)g * D + jg * 4) = ov;
    }
  }
}

extern "C" void kernel_launch(void* const* d_in, const int* in_sizes, int n_in,
                              void* d_out, int out_size, void* d_ws, size_t ws_size,
                              hipStream_t stream) {
  const float* x   = (const float*)d_in[0];
  const void*  ei  = d_in[1];
  const float* eps = (const float*)d_in[2];
  const float* W1  = (const float*)d_in[3];
  const float* b1  = (const float*)d_in[4];
  const float* W2  = (const float*)d_in[5];
  const float* b2  = (const float*)d_in[6];
  float* out = (float*)d_out;

  const int n_nodes = in_sizes[0] / D;
  const int n_edges = in_sizes[1] / 2;
  const int nchunks = (n_edges + CHUNK - 1) / CHUNK;
  const int ntiles = (n_edges + BIN_TILE - 1) / BIN_TILE;

  // Packing geometry: entry = (dstLocal << shift_src) | src (unsigned).
  int shift_src = 0;
  while ((1 << shift_src) < n_nodes) ++shift_src;
  const int caprange = (n_nodes + NGROUP - 1) / NGROUP;
  int bits_dl = 0;
  while ((1 << bits_dl) < caprange + 1) ++bits_dl;
  const bool packok = (shift_src + bits_dl) <= 31;  // reserve SENTINEL

  // Per-(group, xcd-slot) subregion capacity: E/64 + slack + pad allowance.
  int capSub = (n_edges + 63) / 64 + 8192 + 16 * ((ntiles + 7) / 8);
  capSub = (capSub + 15) & ~15;  // keep subregions 64B-aligned

  // ws layouts (ints):
  //  full: bucket[64*capSub] (FIRST: 64B-aligned) | C[n] | bcnt[BCNT_INTS]
  //        | tsum | sorted[E] | cs[nchunks]
  //  mid:  C[n] | bcnt | tsum | sorted[E] | cs[nchunks]
  const size_t base_ints = (size_t)n_nodes + BCNT_INTS + SCAN_CHUNKS +
                           (size_t)n_edges + (size_t)nchunks;
  const size_t need_full = (base_ints + (size_t)64 * capSub) * 4;
  const size_t need_mid = base_ints * 4;

  if (ws_size >= need_mid) {
    const bool full = packok && (ws_size >= need_full);
    unsigned int* bucket = (unsigned int*)d_ws;
    int* C      = full ? ((int*)d_ws + (size_t)64 * capSub) : (int*)d_ws;
    int* bcnt   = C + n_nodes;
    int* tsum   = bcnt + BCNT_INTS;
    int* sorted = tsum + SCAN_CHUNKS;
    int* cs     = sorted + n_edges;

    (void)hipMemsetAsync(C, 0, ((size_t)n_nodes + BCNT_INTS) * 4, stream);
    // agg (= out) pre-zeroed: flat gather atomic-flushes boundary runs and
    // leaves degree-0 rows untouched.
    (void)hipMemsetAsync(out, 0, (size_t)n_nodes * D * sizeof(float), stream);

    if (full) {
      gin_bin<<<ntiles, 256, 0, stream>>>(ei, C, bcnt, bucket, n_edges,
                                          n_nodes, capSub, shift_src);
    } else {
      gin_hist_ranged<<<EDGE_GRID, EDGE_BLOCK, 0, stream>>>(ei, C, n_edges,
                                                            n_nodes);
    }

    const int chunk = (n_nodes + SCAN_CHUNKS - 1) / SCAN_CHUNKS;
    gin_scan_a<<<SCAN_CHUNKS / 256, 256, 0, stream>>>(C, tsum, n_nodes,
                                                      chunk);
    gin_scan_b<<<1, 1024, 0, stream>>>(tsum);
    gin_scan_c<<<SCAN_CHUNKS / 256, 256, 0, stream>>>(C, tsum, n_nodes,
                                                      chunk);

    if (full) {
      gin_place_bucket<<<EDGE_GRID, EDGE_BLOCK, 0, stream>>>(
          bucket, bcnt, C, sorted, n_nodes, capSub, shift_src);
    } else {
      gin_place_ranged<<<EDGE_GRID, EDGE_BLOCK, 0, stream>>>(ei, C, sorted,
                                                             n_edges,
                                                             n_nodes);
    }

    gin_chunkstart<<<(nchunks + 255) / 256, 256, 0, stream>>>(C, cs, n_nodes,
                                                              nchunks);

    const int gather_blocks = (nchunks + 3) / 4;  // 4 waves per block
    gin_gather_flat<<<gather_blocks, 256, 0, stream>>>(x, C, sorted, cs, out,
                                                       n_nodes, n_edges);
  } else {
    (void)hipMemsetAsync(out, 0, (size_t)n_nodes * D * sizeof(float), stream);
    gin_scatter_atomic<<<4096, 256, 0, stream>>>(x, ei, out, n_edges);
  }

  const int mlp_blocks = (n_nodes + 127) / 128;
  gin_mlp_tiled<<<mlp_blocks, 256, 0, stream>>>(x, out, eps, W1, b1, W2, b2,
                                                out, n_nodes);
}

// Round 23
// 216.846 us; speedup vs baseline: 1.2999x; 1.2999x over previous
//
#include <hip/hip_runtime.h>

#define D 64
#define CHUNK 32      // sorted entries per wave in the flat gather
#define NGROUP 8      // dst-range groups (one per XCD)
#define BIN_EPT 4     // edges per thread in the binning kernel
#define BIN_TILE 1024 // edges per tile (256 threads x BIN_EPT)
#define SENTINEL 0xFFFFFFFFu
#define NSLICE 32     // blocks per group in hist/place (256 blocks total)
#define LDS_BINS 12544  // max nodes per group range held in LDS (50KB)

// ---------------------------------------------------------------------------
// edge_index dtype detection (int32 vs int64), done per-block on device.
// ---------------------------------------------------------------------------
#define DETECT_IS64(ei)                                        \
  __shared__ int s_is64;                                       \
  if (threadIdx.x == 0) {                                      \
    const unsigned int* w_ = (const unsigned int*)(ei);        \
    int is64_ = 1;                                             \
    for (int i_ = 0; i_ < 64; ++i_) {                          \
      if (w_[2 * i_ + 1] != 0u) { is64_ = 0; break; }          \
    }                                                          \
    s_is64 = is64_;                                            \
  }                                                            \
  __syncthreads();

#define EDGE_GRID 4096
#define EDGE_BLOCK 256
#define SCAN_CHUNKS 8192

// bcnt layout: counter (g, s) at bcnt[(g*8+s)*16] — one 64B line each,
// only touched by blocks with blockIdx&7==s (XCD-local, r21).
#define BCNT_IDX(g, s) (((g) * 8 + (s)) * 16)
#define BCNT_INTS (NGROUP * 8 * 16)

// ---------------------------------------------------------------------------
// Kernel 1: BIN (no histogram — r22 lesson: the fused 1.6M scattered
// atomicAdd(&C[dst],1) was 51MB of ~32B/atomic write-through at the
// coherence point = the entire 71us dispatch; identical across r20/21/22
// variants because it was never the bucket writes). Per 1024-edge tile:
// LDS-count per group -> XCD-local reservation -> packed line-aligned runs.
// ---------------------------------------------------------------------------
__global__ __launch_bounds__(256) void gin_bin(
    const void* __restrict__ edge_index,
    int* __restrict__ bcnt, unsigned int* __restrict__ bucket,
    int n_edges, int n_nodes, int capSub, int shift_src) {
  DETECT_IS64(edge_index);
  const int* ei32 = (const int*)edge_index;
  const long long* ei64 = (const long long*)edge_index;
  __shared__ int lcnt[NGROUP];
  __shared__ int lbase[NGROUP];
  const int tid = (int)threadIdx.x;
  const int sub = (int)(blockIdx.x & 7);  // this block's XCD slot
  const int ntiles = (n_edges + BIN_TILE - 1) / BIN_TILE;

  for (int t = (int)blockIdx.x; t < ntiles; t += (int)gridDim.x) {
    if (tid < NGROUP) lcnt[tid] = 0;
    __syncthreads();

    int g[BIN_EPT], pos[BIN_EPT];
    unsigned int pk[BIN_EPT];
#pragma unroll
    for (int k = 0; k < BIN_EPT; ++k) {
      const int e = t * BIN_TILE + tid + k * 256;  // coalesced per k
      g[k] = -1;
      if (e < n_edges) {
        int src, dst;
        if (s_is64) {
          src = (int)ei64[e];
          dst = (int)ei64[n_edges + e];
        } else {
          src = ei32[e];
          dst = ei32[n_edges + e];
        }
        const int gg = (int)(((long long)dst * NGROUP) / n_nodes);
        const int nlo = (int)(((long long)n_nodes * gg) / NGROUP);
        g[k] = gg;
        pk[k] = ((unsigned int)(dst - nlo) << shift_src) | (unsigned int)src;
        pos[k] = atomicAdd(&lcnt[gg], 1);       // LDS cursor
      }
    }
    __syncthreads();
    if (tid < NGROUP) {
      const int padded = (lcnt[tid] + 15) & ~15;  // 64B-aligned reservation
      lbase[tid] = atomicAdd(&bcnt[BCNT_IDX(tid, sub)], padded);
    }
    __syncthreads();
#pragma unroll
    for (int k = 0; k < BIN_EPT; ++k) {
      if (g[k] >= 0) {
        bucket[(size_t)(g[k] * 8 + sub) * capSub + lbase[g[k]] + pos[k]] =
            pk[k];
      }
    }
    // sentinel-fill the pad slots (same block owns the whole run)
    for (int gg = 0; gg < NGROUP; ++gg) {
      const int c = lcnt[gg];
      const int padded = (c + 15) & ~15;
      for (int i = c + tid; i < padded; i += 256) {
        bucket[(size_t)(gg * 8 + sub) * capSub + lbase[gg] + i] = SENTINEL;
      }
    }
    __syncthreads();  // protect lcnt reset next iteration
  }
}

// ---------------------------------------------------------------------------
// Kernel 1.5: histogram from buckets via LDS (zero scattered global
// atomics). 32 blocks per group (b&7=g -> XCD g). Each block LDS-counts its
// slice of the group's 8 subregions, then does ONE COALESCED sweep of
// atomicAdd(&C[nlo+j], lh[j]) — contiguous addresses = full-line traffic.
// ---------------------------------------------------------------------------
__global__ __launch_bounds__(256) void gin_hist_bucket(
    const unsigned int* __restrict__ bucket, const int* __restrict__ bcnt,
    int* __restrict__ C, int n_nodes, int capSub, int shift_src) {
  __shared__ int lh[LDS_BINS];
  const int g = (int)(blockIdx.x & (NGROUP - 1));
  const int s2 = (int)(blockIdx.x >> 3);
  const int tid = (int)threadIdx.x;
  const int nlo = (int)(((long long)n_nodes * g) / NGROUP);
  const int nhi = (int)(((long long)n_nodes * (g + 1)) / NGROUP);
  const int nrange = nhi - nlo;

  for (int j = tid; j < nrange; j += 256) lh[j] = 0;
  __syncthreads();

  for (int sub = 0; sub < 8; ++sub) {
    const int cnt = bcnt[BCNT_IDX(g, sub)];
    const unsigned int* bg = bucket + (size_t)(g * 8 + sub) * capSub;
    const int beg = (int)((long long)cnt * s2 / NSLICE);
    const int end = (int)((long long)cnt * (s2 + 1) / NSLICE);
    for (int i = beg + tid; i < end; i += 256) {
      const unsigned int e = bg[i];
      if (e != SENTINEL) atomicAdd(&lh[e >> shift_src], 1);
    }
  }
  __syncthreads();

  for (int j = tid; j < nrange; j += 256) {
    atomicAdd(&C[nlo + j], lh[j]);  // coalesced
  }
}

// ---------------------------------------------------------------------------
// Kernels 2a/2b/2c: in-place exclusive scan of C[total], SCAN_CHUNKS chunks.
// ---------------------------------------------------------------------------
__global__ __launch_bounds__(256) void gin_scan_a(
    const int* __restrict__ C, int* __restrict__ tsum, int total, int chunk) {
  const int t = (int)(blockIdx.x * blockDim.x + threadIdx.x);
  if (t >= SCAN_CHUNKS) return;
  const int beg = t * chunk;
  const int end = min(beg + chunk, total);
  int s = 0;
  for (int i = beg; i < end; ++i) s += C[i];
  tsum[t] = s;
}

__global__ __launch_bounds__(1024) void gin_scan_b(int* __restrict__ tsum) {
  __shared__ int ls[1024];
  const int t = threadIdx.x;
  int v[8];
  int s = 0;
#pragma unroll
  for (int i = 0; i < 8; ++i) {
    v[i] = tsum[t * 8 + i];
    s += v[i];
  }
  ls[t] = s;
  __syncthreads();
  for (int o = 1; o < 1024; o <<= 1) {
    const int a = (t >= o) ? ls[t - o] : 0;
    __syncthreads();
    ls[t] += a;
    __syncthreads();
  }
  int run = ls[t] - s;
#pragma unroll
  for (int i = 0; i < 8; ++i) {
    tsum[t * 8 + i] = run;
    run += v[i];
  }
}

__global__ __launch_bounds__(256) void gin_scan_c(
    int* __restrict__ C, const int* __restrict__ tsum, int total, int chunk) {
  const int t = (int)(blockIdx.x * blockDim.x + threadIdx.x);
  if (t >= SCAN_CHUNKS) return;
  const int beg = t * chunk;
  const int end = min(beg + chunk, total);
  int run = tsum[t];
  for (int i = beg; i < end; ++i) {
    const int c = C[i];
    C[i] = run;
    run += c;
  }
}

// ---------------------------------------------------------------------------
// Kernel 3: two-level placement — LDS count + COALESCED returning reserve +
// LDS cursors. No scattered global atomics (r22 lesson). 32 blocks per
// group; each block: count its slice in LDS -> lh[j]=atomicAdd(&C[nlo+j],v)
// (coalesced, disjoint [base,base+v) per block) -> re-read slice, pos from
// LDS cursor, write sorted[pos]. Sorted region per group = 800KB, single
// XCD -> L2 write-merge. After all blocks: C[k] = prefix[k+1].
// ---------------------------------------------------------------------------
__global__ __launch_bounds__(256) void gin_place_bucket2(
    const unsigned int* __restrict__ bucket, const int* __restrict__ bcnt,
    int* __restrict__ C, int* __restrict__ sorted_src,
    int n_nodes, int capSub, int shift_src) {
  __shared__ int lh[LDS_BINS];
  const int g = (int)(blockIdx.x & (NGROUP - 1));
  const int s2 = (int)(blockIdx.x >> 3);
  const int tid = (int)threadIdx.x;
  const int nlo = (int)(((long long)n_nodes * g) / NGROUP);
  const int nhi = (int)(((long long)n_nodes * (g + 1)) / NGROUP);
  const int nrange = nhi - nlo;
  const unsigned int mask = (1u << shift_src) - 1u;

  for (int j = tid; j < nrange; j += 256) lh[j] = 0;
  __syncthreads();

  // pass 1: count this block's slice
  for (int sub = 0; sub < 8; ++sub) {
    const int cnt = bcnt[BCNT_IDX(g, sub)];
    const unsigned int* bg = bucket + (size_t)(g * 8 + sub) * capSub;
    const int beg = (int)((long long)cnt * s2 / NSLICE);
    const int end = (int)((long long)cnt * (s2 + 1) / NSLICE);
    for (int i = beg + tid; i < end; i += 256) {
      const unsigned int e = bg[i];
      if (e != SENTINEL) atomicAdd(&lh[e >> shift_src], 1);
    }
  }
  __syncthreads();

  // reserve: coalesced returning atomics; lh becomes this block's cursor base
  for (int j = tid; j < nrange; j += 256) {
    lh[j] = atomicAdd(&C[nlo + j], lh[j]);
  }
  __syncthreads();

  // pass 2: place via LDS cursors
  for (int sub = 0; sub < 8; ++sub) {
    const int cnt = bcnt[BCNT_IDX(g, sub)];
    const unsigned int* bg = bucket + (size_t)(g * 8 + sub) * capSub;
    const int beg = (int)((long long)cnt * s2 / NSLICE);
    const int end = (int)((long long)cnt * (s2 + 1) / NSLICE);
    for (int i = beg + tid; i < end; i += 256) {
      const unsigned int e = bg[i];
      if (e != SENTINEL) {
        const int dl = (int)(e >> shift_src);
        const int src = (int)(e & mask);
        const int pos = atomicAdd(&lh[dl], 1);  // LDS returning
        sorted_src[pos] = src;
      }
    }
  }
}

// ---------------------------------------------------------------------------
// Kernel 3.5: per-chunk segment-start lookup. cs[w] = first k, C[k] > w*CHUNK.
// ---------------------------------------------------------------------------
__global__ __launch_bounds__(256) void gin_chunkstart(
    const int* __restrict__ C, int* __restrict__ cs, int n_nodes,
    int nchunks) {
  const int t = (int)(blockIdx.x * blockDim.x + threadIdx.x);
  if (t >= nchunks) return;
  const int start = t * CHUNK;
  int lo = 0, hi = n_nodes - 1;
  while (lo < hi) {
    const int mid = (lo + hi) >> 1;
    if (C[mid] > start) hi = mid; else lo = mid + 1;
  }
  cs[t] = lo;
}

// ---------------------------------------------------------------------------
// Kernel 4: FLAT segmented-sum gather, CHUNK=32, precomputed chunk starts.
// srcs staged into SGPRs (readfirstlane); 32 independent 256B row reads in
// flight. Interior segments plain-store; boundary segments atomicAdd (agg
// pre-zeroed; degree-0 nodes stay zero).
// ---------------------------------------------------------------------------
__global__ __launch_bounds__(256) void gin_gather_flat(
    const float* __restrict__ x, const int* __restrict__ C,
    const int* __restrict__ sorted_src, const int* __restrict__ cs,
    float* __restrict__ agg, int n_nodes, int n_edges) {
  const int lane = (int)(threadIdx.x & 63);
  const int wave = (int)((blockIdx.x * blockDim.x + threadIdx.x) >> 6);
  const int start = wave * CHUNK;
  if (start >= n_edges) return;
  const int cend = min(start + CHUNK, n_edges);

  int srcs[CHUNK];
#pragma unroll
  for (int i = 0; i < CHUNK; ++i) {
    srcs[i] = __builtin_amdgcn_readfirstlane(
        sorted_src[min(start + i, n_edges - 1)]);
  }
  float rows[CHUNK];
#pragma unroll
  for (int i = 0; i < CHUNK; ++i) {
    rows[i] = x[(size_t)srcs[i] * D + lane];
  }

  int k = cs[wave];
  int end = C[k];
  int segbeg = (k == 0) ? 0 : C[k - 1];

  float acc = 0.0f;
  int runstart = start;
#pragma unroll
  for (int i = 0; i < CHUNK; ++i) {
    const int pos = start + i;
    if (pos >= cend) break;  // tail chunk only
    acc += rows[i];
    if (pos + 1 == end) {
      const size_t off = (size_t)k * D + lane;
      if (segbeg >= start) {
        agg[off] = acc;               // interior: sole writer
      } else {
        atomicAdd(&agg[off], acc);    // crosses chunk start
      }
      acc = 0.0f;
      runstart = pos + 1;
      if (pos + 1 < cend) {
        segbeg = end;
        ++k;
        end = C[k];
        while (end == segbeg) { ++k; end = C[k]; }  // skip empty nodes
      }
    }
  }
  if (runstart < cend) {
    atomicAdd(&agg[(size_t)k * D + lane], acc);  // trailing open run
  }
}

// ---------------------------------------------------------------------------
// Mid-path fallback kernels (read edge_index directly; r16 behavior).
// ---------------------------------------------------------------------------
__global__ __launch_bounds__(256) void gin_hist_ranged(
    const void* __restrict__ edge_index, int* __restrict__ C,
    int n_edges, int n_nodes) {
  DETECT_IS64(edge_index);
  const int* ei32 = (const int*)edge_index;
  const long long* ei64 = (const long long*)edge_index;
  const int r = (int)(blockIdx.x & (NGROUP - 1));
  const int nlo = (int)(((long long)n_nodes * r) / NGROUP);
  const int nhi = (int)(((long long)n_nodes * (r + 1)) / NGROUP);
  const int i = (int)((blockIdx.x >> 3) * blockDim.x + threadIdx.x);
  const int stride = (int)((gridDim.x >> 3) * blockDim.x);
  for (int e = i; e < n_edges; e += stride) {
    const int dst = s_is64 ? (int)ei64[n_edges + e] : ei32[n_edges + e];
    if (dst >= nlo && dst < nhi) atomicAdd(&C[dst], 1);
  }
}

__global__ __launch_bounds__(256) void gin_place_ranged(
    const void* __restrict__ edge_index, int* __restrict__ C,
    int* __restrict__ sorted_src, int n_edges, int n_nodes) {
  DETECT_IS64(edge_index);
  const int* ei32 = (const int*)edge_index;
  const long long* ei64 = (const long long*)edge_index;
  const int r = (int)(blockIdx.x & (NGROUP - 1));
  const int nlo = (int)(((long long)n_nodes * r) / NGROUP);
  const int nhi = (int)(((long long)n_nodes * (r + 1)) / NGROUP);
  const int i = (int)((blockIdx.x >> 3) * blockDim.x + threadIdx.x);
  const int stride = (int)((gridDim.x >> 3) * blockDim.x);
  for (int e = i; e < n_edges; e += stride) {
    const int dst = s_is64 ? (int)ei64[n_edges + e] : ei32[n_edges + e];
    if (dst >= nlo && dst < nhi) {
      const int src = s_is64 ? (int)ei64[e] : ei32[e];
      const int pos = atomicAdd(&C[dst], 1);
      sorted_src[pos] = src;
    }
  }
}

// ---------------------------------------------------------------------------
// Last-resort fallback scatter: scalar float atomics, wave per edge.
// ---------------------------------------------------------------------------
__global__ __launch_bounds__(256) void gin_scatter_atomic(
    const float* __restrict__ x, const void* __restrict__ edge_index,
    float* __restrict__ agg, int n_edges) {
  DETECT_IS64(edge_index);
  const int* ei32 = (const int*)edge_index;
  const long long* ei64 = (const long long*)edge_index;
  const int lane = threadIdx.x & 63;
  int wave = (int)((blockIdx.x * blockDim.x + threadIdx.x) >> 6);
  const int nwaves = (int)((gridDim.x * blockDim.x) >> 6);
  for (int e = wave; e < n_edges; e += nwaves) {
    int src, dst;
    if (s_is64) {
      src = (int)ei64[e];
      dst = (int)ei64[n_edges + e];
    } else {
      src = ei32[e];
      dst = ei32[n_edges + e];
    }
    atomicAdd(&agg[(size_t)dst * D + lane], x[(size_t)src * D + lane]);
  }
}

// ---------------------------------------------------------------------------
// Kernel 5: block-tiled MLP (vector f32 GEMM). Unchanged from round 10/11.
// ---------------------------------------------------------------------------
__global__ __launch_bounds__(256) void gin_mlp_tiled(
    const float* __restrict__ x,
    const float* __restrict__ agg_in,
    const float* __restrict__ eps_p,
    const float* __restrict__ W1, const float* __restrict__ b1,
    const float* __restrict__ W2, const float* __restrict__ b2,
    float* __restrict__ out,
    int n_nodes) {
  __shared__ float zs[128 * 72];   // z tile; reused for h
  __shared__ float w1s[64 * 64];
  __shared__ float w2s[64 * 64];

  const int t = (int)threadIdx.x;
  const int base = (int)blockIdx.x * 128;
  const float scale = 1.0f + eps_p[0];

  {
    const float4* W1v = (const float4*)W1;
    const float4* W2v = (const float4*)W2;
#pragma unroll
    for (int i = 0; i < 4; ++i) {
      const int idx = t + 256 * i;
      const int j = idx >> 4;
      const int kq = idx & 15;
      const int slot = kq ^ ((j >> 2) & 7);
      *(float4*)&w1s[j * 64 + slot * 4] = W1v[idx];
      *(float4*)&w2s[j * 64 + slot * 4] = W2v[idx];
    }
  }

  {
#pragma unroll
    for (int i = 0; i < 8; ++i) {
      const int idx = t + 256 * i;
      const int row = idx >> 4;
      const int kq = idx & 15;
      const int g = base + row;
      float4 zv;
      zv.x = 0.0f; zv.y = 0.0f; zv.z = 0.0f; zv.w = 0.0f;
      if (g < n_nodes) {
        const float4 xv = *(const float4*)(x + (size_t)g * D + kq * 4);
        const float4 av = *(const float4*)(agg_in + (size_t)g * D + kq * 4);
        zv.x = scale * xv.x + av.x;
        zv.y = scale * xv.y + av.y;
        zv.z = scale * xv.z + av.z;
        zv.w = scale * xv.w + av.w;
      }
      *(float4*)&zs[row * 72 + kq * 4] = zv;
    }
  }
  __syncthreads();

  const int jg = t & 15;
  const int mg = t >> 4;
  const float4 b1q = ((const float4*)b1)[jg];
  const float4 b2q = ((const float4*)b2)[jg];
  const int wswz = (jg & 7);

  float acc[8][4];
#pragma unroll
  for (int r = 0; r < 8; ++r) {
    acc[r][0] = b1q.x; acc[r][1] = b1q.y;
    acc[r][2] = b1q.z; acc[r][3] = b1q.w;
  }

#pragma unroll 4
  for (int kq = 0; kq < 16; ++kq) {
    float4 wq[4];
#pragma unroll
    for (int c = 0; c < 4; ++c) {
      wq[c] = *(const float4*)&w1s[(4 * jg + c) * 64 + ((kq ^ wswz) * 4)];
    }
#pragma unroll
    for (int r = 0; r < 8; ++r) {
      const float4 zq = *(const float4*)&zs[(r * 16 + mg) * 72 + kq * 4];
#pragma unroll
      for (int c = 0; c < 4; ++c) {
        acc[r][c] += zq.x * wq[c].x + zq.y * wq[c].y +
                     zq.z * wq[c].z + zq.w * wq[c].w;
      }
    }
  }

  __syncthreads();
#pragma unroll
  for (int r = 0; r < 8; ++r) {
    float4 hv;
    hv.x = fmaxf(acc[r][0], 0.0f);
    hv.y = fmaxf(acc[r][1], 0.0f);
    hv.z = fmaxf(acc[r][2], 0.0f);
    hv.w = fmaxf(acc[r][3], 0.0f);
    *(float4*)&zs[(r * 16 + mg) * 72 + jg * 4] = hv;
  }
  __syncthreads();

#pragma unroll
  for (int r = 0; r < 8; ++r) {
    acc[r][0] = b2q.x; acc[r][1] = b2q.y;
    acc[r][2] = b2q.z; acc[r][3] = b2q.w;
  }
#pragma unroll 4
  for (int kq = 0; kq < 16; ++kq) {
    float4 wq[4];
#pragma unroll
    for (int c = 0; c < 4; ++c) {
      wq[c] = *(const float4*)&w2s[(4 * jg + c) * 64 + ((kq ^ wswz) * 4)];
    }
#pragma unroll
    for (int r = 0; r < 8; ++r) {
      const float4 zq = *(const float4*)&zs[(r * 16 + mg) * 72 + kq * 4];
#pragma unroll
      for (int c = 0; c < 4; ++c) {
        acc[r][c] += zq.x * wq[c].x + zq.y * wq[c].y +
                     zq.z * wq[c].z + zq.w * wq[c].w;
      }
    }
  }

#pragma unroll
  for (int r = 0; r < 8; ++r) {
    const int g = base + r * 16 + mg;
    if (g < n_nodes) {
      float4 ov;
      ov.x = acc[r][0]; ov.y = acc[r][1];
      ov.z = acc[r][2]; ov.w = acc[r][3];
      *(float4*)(out + (size_t)g * D + jg * 4) = ov;
    }
  }
}

extern "C" void kernel_launch(void* const* d_in, const int* in_sizes, int n_in,
                              void* d_out, int out_size, void* d_ws, size_t ws_size,
                              hipStream_t stream) {
  const float* x   = (const float*)d_in[0];
  const void*  ei  = d_in[1];
  const float* eps = (const float*)d_in[2];
  const float* W1  = (const float*)d_in[3];
  const float* b1  = (const float*)d_in[4];
  const float* W2  = (const float*)d_in[5];
  const float* b2  = (const float*)d_in[6];
  float* out = (float*)d_out;

  const int n_nodes = in_sizes[0] / D;
  const int n_edges = in_sizes[1] / 2;
  const int nchunks = (n_edges + CHUNK - 1) / CHUNK;
  const int ntiles = (n_edges + BIN_TILE - 1) / BIN_TILE;

  // Packing geometry: entry = (dstLocal << shift_src) | src (unsigned).
  int shift_src = 0;
  while ((1 << shift_src) < n_nodes) ++shift_src;
  const int caprange = (n_nodes + NGROUP - 1) / NGROUP;
  int bits_dl = 0;
  while ((1 << bits_dl) < caprange + 1) ++bits_dl;
  const bool packok =
      ((shift_src + bits_dl) <= 31) && (caprange <= LDS_BINS);

  // Per-(group, xcd-slot) subregion capacity: E/64 + slack + pad allowance.
  int capSub = (n_edges + 63) / 64 + 8192 + 16 * ((ntiles + 7) / 8);
  capSub = (capSub + 15) & ~15;  // keep subregions 64B-aligned

  // ws layouts (ints):
  //  full: bucket[64*capSub] (FIRST: 64B-aligned) | C[n] | bcnt[BCNT_INTS]
  //        | tsum | sorted[E] | cs[nchunks]
  //  mid:  C[n] | bcnt | tsum | sorted[E] | cs[nchunks]
  const size_t base_ints = (size_t)n_nodes + BCNT_INTS + SCAN_CHUNKS +
                           (size_t)n_edges + (size_t)nchunks;
  const size_t need_full = (base_ints + (size_t)64 * capSub) * 4;
  const size_t need_mid = base_ints * 4;

  if (ws_size >= need_mid) {
    const bool full = packok && (ws_size >= need_full);
    unsigned int* bucket = (unsigned int*)d_ws;
    int* C      = full ? ((int*)d_ws + (size_t)64 * capSub) : (int*)d_ws;
    int* bcnt   = C + n_nodes;
    int* tsum   = bcnt + BCNT_INTS;
    int* sorted = tsum + SCAN_CHUNKS;
    int* cs     = sorted + n_edges;

    (void)hipMemsetAsync(C, 0, ((size_t)n_nodes + BCNT_INTS) * 4, stream);
    // agg (= out) pre-zeroed: flat gather atomic-flushes boundary runs and
    // leaves degree-0 rows untouched.
    (void)hipMemsetAsync(out, 0, (size_t)n_nodes * D * sizeof(float), stream);

    if (full) {
      gin_bin<<<ntiles, 256, 0, stream>>>(ei, bcnt, bucket, n_edges,
                                          n_nodes, capSub, shift_src);
      gin_hist_bucket<<<NGROUP * NSLICE, 256, 0, stream>>>(
          bucket, bcnt, C, n_nodes, capSub, shift_src);
    } else {
      gin_hist_ranged<<<EDGE_GRID, EDGE_BLOCK, 0, stream>>>(ei, C, n_edges,
                                                            n_nodes);
    }

    const int chunk = (n_nodes + SCAN_CHUNKS - 1) / SCAN_CHUNKS;
    gin_scan_a<<<SCAN_CHUNKS / 256, 256, 0, stream>>>(C, tsum, n_nodes,
                                                      chunk);
    gin_scan_b<<<1, 1024, 0, stream>>>(tsum);
    gin_scan_c<<<SCAN_CHUNKS / 256, 256, 0, stream>>>(C, tsum, n_nodes,
                                                      chunk);

    if (full) {
      gin_place_bucket2<<<NGROUP * NSLICE, 256, 0, stream>>>(
          bucket, bcnt, C, sorted, n_nodes, capSub, shift_src);
    } else {
      gin_place_ranged<<<EDGE_GRID, EDGE_BLOCK, 0, stream>>>(ei, C, sorted,
                                                             n_edges,
                                                             n_nodes);
    }

    gin_chunkstart<<<(nchunks + 255) / 256, 256, 0, stream>>>(C, cs, n_nodes,
                                                              nchunks);

    const int gather_blocks = (nchunks + 3) / 4;  // 4 waves per block
    gin_gather_flat<<<gather_blocks, 256, 0, stream>>>(x, C, sorted, cs, out,
                                                       n_nodes, n_edges);
  } else {
    (void)hipMemsetAsync(out, 0, (size_t)n_nodes * D * sizeof(float), stream);
    gin_scatter_atomic<<<4096, 256, 0, stream>>>(x, ei, out, n_edges);
  }

  const int mlp_blocks = (n_nodes + 127) / 128;
  gin_mlp_tiled<<<mlp_blocks, 256, 0, stream>>>(x, out, eps, W1, b1, W2, b2,
                                                out, n_nodes);
}